// Round 2
// baseline (87.007 us; speedup 1.0000x reference)
//
#include <hip/hip_runtime.h>
#include <stdint.h>

#define N 8192
#define MAX_E (64 * N)          // 524288
#define NCHUNK (N / 64)         // 128 mask chunks per row
#define NCOL1 9                 // 9x9x9 grid, width 50/9 = 5.556 > 5 + eps
#define NCELLS (NCOL1 * NCOL1 * NCOL1)   // 729 cells
#define SCALE (9.0f / 50.0f)
#define M_WAVES 4               // rows per mask block (1 row per wave)
#define E_BLOCKS 256            // emit blocks (32 rows each)
#define E_ROWS 32

// Exact replication of numpy f32: sum(pos*pos, -1) = ((x*x)+(y*y))+(z*z),
// each product rounded (no fma).
__device__ __forceinline__ float sq_exact(float x, float y, float z) {
    return __fadd_rn(__fadd_rn(__fmul_rn(x, x), __fmul_rn(y, y)), __fmul_rn(z, z));
}

// d2 = RN(sqsum - RN(2*dot)); 2*dot is exact so fma(-2,dot,sqsum) is bit-identical.
// dist<5 <=> d2 < 0x1.8ffffep+4f (largest f32 below 25 has correctly-rounded sqrt
// equal to exactly 5.0, so that value must be excluded).
// |computed d2 - true d^2| <= ~7e-3, so pairs whose cells differ by >=2 in ANY
// coordinate have computed d2 > 30.8 >> threshold -> provably non-edges; the
// 3x3x3 neighbor-cell filter is bit-exact.
__device__ __forceinline__ bool edge_pred(float xi, float yi, float zi, float sqi,
                                          const float4& pj) {
    float dot = __fmaf_rn(zi, pj.z, __fmaf_rn(yi, pj.y, __fmul_rn(xi, pj.x)));
    float d2  = __fmaf_rn(-2.0f, dot, __fadd_rn(sqi, pj.w));
    return d2 < 0x1.8ffffep+4f;
}

__device__ __forceinline__ int cell_of(float v) {
    int c = (int)(__fmul_rn(v, SCALE));
    return c > 8 ? 8 : c;       // v=49.99999 -> product can round to 9.0
}

__device__ __forceinline__ int cell3_of(float x, float y, float z) {
    return (cell_of(x) * NCOL1 + cell_of(y)) * NCOL1 + cell_of(z);
}

// Fused binning: count + scan + scatter in ONE single-block kernel.
// 1024 threads, 8 points/thread held in registers across the whole kernel.
// Counts, scan, and scatter cursors all live in LDS (729 ints) -> no global
// atomics, no poison dependence, no inter-kernel traffic except the outputs.
// Replaces the previous count/scan/scatter trio (saves 2 launches + two
// rounds of contended L2 atomics on 46 cache lines).
__global__ __launch_bounds__(1024) void bin_kernel(const float* __restrict__ posf,
                                                   int* __restrict__ cbase_g,
                                                   float4* __restrict__ colpts,
                                                   int* __restrict__ colidx) {
    __shared__ int lcnt[NCELLS];   // counts, then scatter cursors
    __shared__ int part[256];
    const int tid = threadIdx.x;

    for (int k = tid; k < NCELLS; k += 1024) lcnt[k] = 0;

    // load points [8*tid, 8*tid+8) as 6 float4 (96B/thread, fully coalesced)
    const float4* p4 = (const float4*)posf;
    float4 f[6];
#pragma unroll
    for (int k = 0; k < 6; k++) f[k] = p4[tid * 6 + k];
    float px[8], py[8], pz[8];
    px[0]=f[0].x; py[0]=f[0].y; pz[0]=f[0].z;
    px[1]=f[0].w; py[1]=f[1].x; pz[1]=f[1].y;
    px[2]=f[1].z; py[2]=f[1].w; pz[2]=f[2].x;
    px[3]=f[2].y; py[3]=f[2].z; pz[3]=f[2].w;
    px[4]=f[3].x; py[4]=f[3].y; pz[4]=f[3].z;
    px[5]=f[3].w; py[5]=f[4].x; pz[5]=f[4].y;
    px[6]=f[4].z; py[6]=f[4].w; pz[6]=f[5].x;
    px[7]=f[5].y; py[7]=f[5].z; pz[7]=f[5].w;

    __syncthreads();               // lcnt zeroed
    int cell[8];
#pragma unroll
    for (int k = 0; k < 8; k++) {
        cell[k] = cell3_of(px[k], py[k], pz[k]);
        atomicAdd(&lcnt[cell[k]], 1);
    }
    __syncthreads();

    // exclusive scan of 729 counts (256 threads x 3 cells), rest idle but sync
    int c0 = 0, c1 = 0, c2 = 0, s = 0;
    const int i0 = tid * 3;
    if (tid < 256) {
        c0 = (i0 + 0 < NCELLS) ? lcnt[i0 + 0] : 0;
        c1 = (i0 + 1 < NCELLS) ? lcnt[i0 + 1] : 0;
        c2 = (i0 + 2 < NCELLS) ? lcnt[i0 + 2] : 0;
        s = c0 + c1 + c2;
        part[tid] = s;
    }
    __syncthreads();
    for (int off = 1; off < 256; off <<= 1) {
        int v = 0;
        if (tid >= off && tid < 256) v = part[tid - off];
        __syncthreads();
        if (tid < 256) part[tid] += v;
        __syncthreads();
    }
    if (tid < 256) {
        int run = part[tid] - s;   // exclusive prefix
        if (i0 + 0 < NCELLS) { cbase_g[i0 + 0] = run; lcnt[i0 + 0] = run; run += c0; }
        if (i0 + 1 < NCELLS) { cbase_g[i0 + 1] = run; lcnt[i0 + 1] = run; run += c1; }
        if (i0 + 2 < NCELLS) { cbase_g[i0 + 2] = run; lcnt[i0 + 2] = run; run += c2; }
    }
    if (tid == 255) cbase_g[NCELLS] = part[255];   // = N
    __syncthreads();

    // scatter via LDS cursors; slot order within a cell is nondeterministic ->
    // irrelevant (masks are positional bits). All 8192 slots exactly filled.
#pragma unroll
    for (int k = 0; k < 8; k++) {
        const int slot = atomicAdd(&lcnt[cell[k]], 1);
        colpts[slot] = make_float4(px[k], py[k], pz[k],
                                   sq_exact(px[k], py[k], pz[k]));
        colidx[slot] = tid * 8 + k;
    }
}

// Pass 1: one wave per row. 3D binning + compaction: each row scans 9
// CONTIGUOUS ranges (z-window [cz-1,cz+1] of each neighbor column), ~306 avg
// candidates. Also blanket-fills out[] with -1 (2 ints/thread, hidden under
// gather latency) so emit needs no data-dependent tail fill.
// NO fences (R8 lesson); inter-kernel visibility guaranteed by stream order.
__global__ __launch_bounds__(256) void mask_kernel(const float* __restrict__ posf,
                                                   const int* __restrict__ cbase,
                                                   const float4* __restrict__ colpts,
                                                   const int* __restrict__ colidx,
                                                   uint64_t* __restrict__ masks,
                                                   int* __restrict__ counts,
                                                   int* __restrict__ out) {
    __shared__ uint32_t lmask[M_WAVES][256];   // 1KB bitmap per row
    const int tid  = threadIdx.x;
    const int wave = tid >> 6;
    const int lane = tid & 63;
    const int row  = blockIdx.x * M_WAVES + wave;

    // -1 prefill of the whole output (2*MAX_E ints == 2048*256 int2 exactly);
    // emit later overwrites [0, E) with edges.
    int2 neg; neg.x = -1; neg.y = -1;
    ((int2*)out)[blockIdx.x * 256 + tid] = neg;

#pragma unroll
    for (int k = lane; k < 256; k += 64) lmask[wave][k] = 0;

    const float xi = posf[3 * row], yi = posf[3 * row + 1], zi = posf[3 * row + 2];
    const float sqi = sq_exact(xi, yi, zi);
    const int cx = cell_of(xi), cy = cell_of(yi), cz = cell_of(zi);
    const int zlo = (cz > 0) ? cz - 1 : 0;
    const int zhi = (cz < 8) ? cz + 1 : 8;
    __syncthreads();

    // Prefetch all 9 range descriptors up front (fully unrolled -> registers;
    // invalid neighbor columns collapse to zero-length ranges).
    int starts[9], ends[9];
#pragma unroll
    for (int q = 0; q < 9; q++) {
        const int nx = cx + q / 3 - 1;
        const int ny = cy + q % 3 - 1;
        const bool v = ((unsigned)nx <= 8u) & ((unsigned)ny <= 8u);
        const int col = v ? nx * NCOL1 + ny : 0;
        const int s0 = cbase[col * NCOL1 + zlo];
        const int e0 = cbase[col * NCOL1 + zhi + 1];
        starts[q] = s0;
        ends[q]   = v ? e0 : s0;
    }

#pragma unroll
    for (int q = 0; q < 9; q++) {
        for (int k = starts[q] + lane; k < ends[q]; k += 64) {
            float4 pj = colpts[k];
            int j = colidx[k];
            if (j != row && edge_pred(xi, yi, zi, sqi, pj))
                atomicOr(&lmask[wave][j >> 5], 1u << (j & 31));
        }
    }
    __syncthreads();

    // readback: lane l holds words 4l..4l+3 = chunks 2l, 2l+1
    uint4 u = ((const uint4*)lmask[wave])[lane];
    uint64_t k0 = (uint64_t)u.x | ((uint64_t)u.y << 32);
    uint64_t k1 = (uint64_t)u.z | ((uint64_t)u.w << 32);
    ulonglong2 v; v.x = k0; v.y = k1;
    ((ulonglong2*)(masks + (size_t)row * NCHUNK))[lane] = v;
    int t = __popcll(k0) + __popcll(k1);
#pragma unroll
    for (int o = 32; o > 0; o >>= 1) t += __shfl_down(t, o);
    if (lane == 0) counts[row] = t;
}

// Pass 2: masks -> ordered edge list. 256 blocks x 32 rows (halved redundant
// scan work vs 512x16). Each block recomputes the row-offset scan from counts
// (32KB, L2-hot; no inter-block comms, no fence). No tail fill (done in mask).
__global__ __launch_bounds__(256) void emit_kernel(const uint64_t* __restrict__ masks,
                                                   const int* __restrict__ counts,
                                                   int* __restrict__ out) {
    const int tid  = threadIdx.x;
    const int wave = tid >> 6;
    const int lane = tid & 63;
    const int row0 = blockIdx.x * E_ROWS;

    __shared__ int part[256];
    __shared__ int excl32[32];

    // thread t sums rows [t*32, t*32+32)
    const int4* c4 = (const int4*)counts;
    int s = 0;
#pragma unroll
    for (int k = 0; k < 8; k++) {
        int4 v = c4[tid * 8 + k];
        s += v.x + v.y + v.z + v.w;
    }
    part[tid] = s;
    if (tid < 32) excl32[tid] = counts[row0 + tid];
    __syncthreads();
    for (int off = 1; off < 256; off <<= 1) {
        int v = (tid >= off) ? part[tid - off] : 0;
        __syncthreads();
        part[tid] += v;
        __syncthreads();
    }
    if (tid == 0) {                            // tiny LDS-local 32-scan
        int run = 0;
#pragma unroll
        for (int k = 0; k < 32; k++) { int c = excl32[k]; excl32[k] = run; run += c; }
    }
    __syncthreads();
    const int base = (blockIdx.x > 0) ? part[blockIdx.x - 1] : 0;

#pragma unroll
    for (int r = 0; r < 8; r++) {
        const int lr  = wave * 8 + r;          // 0..31
        const int row = row0 + lr;
        ulonglong2 v = ((const ulonglong2*)(masks + (size_t)row * NCHUNK))[lane];
        int s0 = __popcll(v.x), s1 = __popcll(v.y);
        int x = s0 + s1;
#pragma unroll
        for (int o = 1; o < 64; o <<= 1) {
            int t = __shfl_up(x, o);
            if (lane >= o) x += t;
        }
        int slot = base + excl32[lr] + (x - (s0 + s1));

        const int col0 = lane * 128;
        uint64_t m = v.x;
        while (m) {
            int b = __ffsll((unsigned long long)m) - 1;
            m &= m - 1;
            if (slot < MAX_E) { out[slot] = row; out[MAX_E + slot] = col0 + b; }
            slot++;
        }
        m = v.y;
        while (m) {
            int b = __ffsll((unsigned long long)m) - 1;
            m &= m - 1;
            if (slot < MAX_E) { out[slot] = row; out[MAX_E + slot] = col0 + 64 + b; }
            slot++;
        }
    }
}

extern "C" void kernel_launch(void* const* d_in, const int* in_sizes, int n_in,
                              void* d_out, int out_size, void* d_ws, size_t ws_size,
                              hipStream_t stream) {
    const float* posf = (const float*)d_in[0];
    int* out = (int*)d_out;
    char* ws = (char*)d_ws;
    int*      counts = (int*)ws;                        // 32KB @ 0
    int*      cbase  = (int*)(ws + (72 << 10));         // 730 ints @ 72KB
    int*      colidx = (int*)(ws + (128 << 10));        // 8192 ints = 32KB @ 128KB
    float4*   colpts = (float4*)(ws + (192 << 10));     // 8192 float4 = 128KB @ 192KB
    uint64_t* masks  = (uint64_t*)(ws + (1 << 20));     // 8MB @ 1MB

    bin_kernel<<<1, 1024, 0, stream>>>(posf, cbase, colpts, colidx);
    mask_kernel<<<N / M_WAVES, 256, 0, stream>>>(posf, cbase, colpts, colidx,
                                                 masks, counts, out);
    emit_kernel<<<E_BLOCKS, 256, 0, stream>>>(masks, counts, out);
}

// Round 4
// 82.102 us; speedup vs baseline: 1.0597x; 1.0597x over previous
//
#include <hip/hip_runtime.h>
#include <stdint.h>

#define N 8192
#define MAX_E (64 * N)          // 524288
#define NCHUNK (N / 64)         // 128 mask chunks per row
#define NCOL1 9                 // 9x9x9 grid, width 50/9 = 5.556 > 5 + eps
#define NCELLS (NCOL1 * NCOL1 * NCOL1)   // 729 cells
#define SCALE (9.0f / 50.0f)
#define POISON 0xAAAAAAAAu      // harness poisons d_ws to 0xAA before EVERY launch
#define M_WAVES 4               // rows per mask block (1 row per wave)
#define E_BLOCKS 256            // emit blocks (32 rows each)
#define E_ROWS 32

// Exact replication of numpy f32: sum(pos*pos, -1) = ((x*x)+(y*y))+(z*z),
// each product rounded (no fma).
__device__ __forceinline__ float sq_exact(float x, float y, float z) {
    return __fadd_rn(__fadd_rn(__fmul_rn(x, x), __fmul_rn(y, y)), __fmul_rn(z, z));
}

// d2 = RN(sqsum - RN(2*dot)); 2*dot is exact so fma(-2,dot,sqsum) is bit-identical.
// dist<5 <=> d2 < 0x1.8ffffep+4f (largest f32 below 25 has correctly-rounded sqrt
// equal to exactly 5.0, so that value must be excluded).
// |computed d2 - true d^2| <= ~7e-3, so pairs whose cells differ by >=2 in ANY
// coordinate have computed d2 > 30.8 >> threshold -> provably non-edges; the
// 3x3x3 neighbor-cell filter is bit-exact.
__device__ __forceinline__ bool edge_pred(float xi, float yi, float zi, float sqi,
                                          const float4& pj) {
    float dot = __fmaf_rn(zi, pj.z, __fmaf_rn(yi, pj.y, __fmul_rn(xi, pj.x)));
    float d2  = __fmaf_rn(-2.0f, dot, __fadd_rn(sqi, pj.w));
    return d2 < 0x1.8ffffep+4f;
}

__device__ __forceinline__ int cell_of(float v) {
    int c = (int)(__fmul_rn(v, SCALE));
    return c > 8 ? 8 : c;       // v=49.99999 -> product can round to 9.0
}

__device__ __forceinline__ int cell3_of(float x, float y, float z) {
    return (cell_of(x) * NCOL1 + cell_of(y)) * NCOL1 + cell_of(z);
}

// Pass A: count points per 3D cell. 32 parallel blocks, 8192 global atomics
// over 729 counters (~11 deep). Counts ride on the 0xAA poison base
// (documented harness contract); consumers subtract POISON.
// R2 lesson: binning must stay WIDE — single-block fusion serialized ~12us
// on one CU and regressed; launches are cheaper than 1/256th of the machine.
__global__ __launch_bounds__(256) void count_kernel(const float* __restrict__ posf,
                                                    unsigned* __restrict__ gcount) {
    const int i = blockIdx.x * 256 + threadIdx.x;   // grid = 32 blocks
    float x = posf[3 * i], y = posf[3 * i + 1], z = posf[3 * i + 2];
    atomicAdd(&gcount[cell3_of(x, y, z)], 1u);
}

// Pass B (fused scan+scatter): each of the 32 blocks redundantly loads the 729
// final counts (3KB, L2-hot) and exclusive-scans them in LDS -- redundancy is
// free at this size and removes the dedicated single-block scan launch.
// Block 0 publishes cbase[730] for mask (stream order covers visibility).
// Slot assignment: cbase[cell] + (atomicAdd(cursor[cell]) - POISON); cursor is
// a second poisoned region, so no init pass and no cross-block ordering.
// Compaction => z-cells contiguous, all 8192 slots exactly written.
__global__ __launch_bounds__(256) void scatter_kernel(const float* __restrict__ posf,
                                                      const unsigned* __restrict__ gcount,
                                                      unsigned* __restrict__ cursor,
                                                      int* __restrict__ cbase_g,
                                                      float4* __restrict__ colpts,
                                                      int* __restrict__ colidx) {
    __shared__ int part[256];
    __shared__ int cb[NCELLS];
    const int tid = threadIdx.x;
    const int i0 = tid * 3;
    const int c0 = (i0 + 0 < NCELLS) ? (int)(gcount[i0 + 0] - POISON) : 0;
    const int c1 = (i0 + 1 < NCELLS) ? (int)(gcount[i0 + 1] - POISON) : 0;
    const int c2 = (i0 + 2 < NCELLS) ? (int)(gcount[i0 + 2] - POISON) : 0;
    const int s = c0 + c1 + c2;
    part[tid] = s;
    __syncthreads();
    for (int off = 1; off < 256; off <<= 1) {
        int v = (tid >= off) ? part[tid - off] : 0;
        __syncthreads();
        part[tid] += v;
        __syncthreads();
    }
    int run = part[tid] - s;                        // exclusive prefix
    if (i0 + 0 < NCELLS) { cb[i0 + 0] = run; run += c0; }
    if (i0 + 1 < NCELLS) { cb[i0 + 1] = run; run += c1; }
    if (i0 + 2 < NCELLS) { cb[i0 + 2] = run; run += c2; }
    if (blockIdx.x == 0) {
        int r2 = part[tid] - s;
        if (i0 + 0 < NCELLS) { cbase_g[i0 + 0] = r2; r2 += c0; }
        if (i0 + 1 < NCELLS) { cbase_g[i0 + 1] = r2; r2 += c1; }
        if (i0 + 2 < NCELLS) { cbase_g[i0 + 2] = r2; r2 += c2; }
        if (tid == 255) cbase_g[NCELLS] = part[255];   // = N = 8192
    }
    __syncthreads();

    const int i = blockIdx.x * 256 + tid;
    float x = posf[3 * i], y = posf[3 * i + 1], z = posf[3 * i + 2];
    const int cell = cell3_of(x, y, z);
    const int slot = cb[cell] + (int)(atomicAdd(&cursor[cell], 1u) - POISON);
    colpts[slot] = make_float4(x, y, z, sq_exact(x, y, z));
    colidx[slot] = i;
}

// Pass 1: one wave per row. 3D binning + compaction: each row scans 9
// CONTIGUOUS ranges (z-window [cz-1,cz+1] of each neighbor column), ~306 avg
// candidates. Also blanket-fills out[] with -1 (one int2/thread, hidden under
// gather latency) so emit needs no data-dependent tail fill.
// NO fences (R8 lesson); inter-kernel visibility guaranteed by stream order.
__global__ __launch_bounds__(256) void mask_kernel(const float* __restrict__ posf,
                                                   const int* __restrict__ cbase,
                                                   const float4* __restrict__ colpts,
                                                   const int* __restrict__ colidx,
                                                   uint64_t* __restrict__ masks,
                                                   int* __restrict__ counts,
                                                   int* __restrict__ out) {
    __shared__ uint32_t lmask[M_WAVES][256];   // 1KB bitmap per row
    const int tid  = threadIdx.x;
    const int wave = tid >> 6;
    const int lane = tid & 63;
    const int row  = blockIdx.x * M_WAVES + wave;

    // -1 prefill of the whole output (2*MAX_E ints == 2048*256 int2 exactly);
    // emit later overwrites [0, E) with edges.
    int2 neg; neg.x = -1; neg.y = -1;
    ((int2*)out)[blockIdx.x * 256 + tid] = neg;

#pragma unroll
    for (int k = lane; k < 256; k += 64) lmask[wave][k] = 0;

    const float xi = posf[3 * row], yi = posf[3 * row + 1], zi = posf[3 * row + 2];
    const float sqi = sq_exact(xi, yi, zi);
    const int cx = cell_of(xi), cy = cell_of(yi), cz = cell_of(zi);
    const int zlo = (cz > 0) ? cz - 1 : 0;
    const int zhi = (cz < 8) ? cz + 1 : 8;
    __syncthreads();

    // Prefetch all 9 range descriptors up front (fully unrolled -> registers;
    // invalid neighbor columns collapse to zero-length ranges).
    int starts[9], ends[9];
#pragma unroll
    for (int q = 0; q < 9; q++) {
        const int nx = cx + q / 3 - 1;
        const int ny = cy + q % 3 - 1;
        const bool v = ((unsigned)nx <= 8u) & ((unsigned)ny <= 8u);
        const int col = v ? nx * NCOL1 + ny : 0;
        const int s0 = cbase[col * NCOL1 + zlo];
        const int e0 = cbase[col * NCOL1 + zhi + 1];
        starts[q] = s0;
        ends[q]   = v ? e0 : s0;
    }

#pragma unroll
    for (int q = 0; q < 9; q++) {
        for (int k = starts[q] + lane; k < ends[q]; k += 64) {
            float4 pj = colpts[k];
            int j = colidx[k];
            if (j != row && edge_pred(xi, yi, zi, sqi, pj))
                atomicOr(&lmask[wave][j >> 5], 1u << (j & 31));
        }
    }
    __syncthreads();

    // readback: lane l holds words 4l..4l+3 = chunks 2l, 2l+1
    uint4 u = ((const uint4*)lmask[wave])[lane];
    uint64_t k0 = (uint64_t)u.x | ((uint64_t)u.y << 32);
    uint64_t k1 = (uint64_t)u.z | ((uint64_t)u.w << 32);
    ulonglong2 v; v.x = k0; v.y = k1;
    ((ulonglong2*)(masks + (size_t)row * NCHUNK))[lane] = v;
    int t = __popcll(k0) + __popcll(k1);
#pragma unroll
    for (int o = 32; o > 0; o >>= 1) t += __shfl_down(t, o);
    if (lane == 0) counts[row] = t;
}

// Pass 2: masks -> ordered edge list. 256 blocks x 32 rows. Each block
// redundantly recomputes the row-offset scan from counts (32KB, L2-hot;
// no inter-block comms, no fence). No tail fill (done in mask).
__global__ __launch_bounds__(256) void emit_kernel(const uint64_t* __restrict__ masks,
                                                   const int* __restrict__ counts,
                                                   int* __restrict__ out) {
    const int tid  = threadIdx.x;
    const int wave = tid >> 6;
    const int lane = tid & 63;
    const int row0 = blockIdx.x * E_ROWS;

    __shared__ int part[256];
    __shared__ int excl32[32];

    // thread t sums rows [t*32, t*32+32)
    const int4* c4 = (const int4*)counts;
    int s = 0;
#pragma unroll
    for (int k = 0; k < 8; k++) {
        int4 v = c4[tid * 8 + k];
        s += v.x + v.y + v.z + v.w;
    }
    part[tid] = s;
    if (tid < 32) excl32[tid] = counts[row0 + tid];
    __syncthreads();
    for (int off = 1; off < 256; off <<= 1) {
        int v = (tid >= off) ? part[tid - off] : 0;
        __syncthreads();
        part[tid] += v;
        __syncthreads();
    }
    if (tid == 0) {                            // tiny LDS-local 32-scan
        int run = 0;
#pragma unroll
        for (int k = 0; k < 32; k++) { int c = excl32[k]; excl32[k] = run; run += c; }
    }
    __syncthreads();
    const int base = (blockIdx.x > 0) ? part[blockIdx.x - 1] : 0;

#pragma unroll
    for (int r = 0; r < 8; r++) {
        const int lr  = wave * 8 + r;          // 0..31
        const int row = row0 + lr;
        ulonglong2 v = ((const ulonglong2*)(masks + (size_t)row * NCHUNK))[lane];
        int s0 = __popcll(v.x), s1 = __popcll(v.y);
        int x = s0 + s1;
#pragma unroll
        for (int o = 1; o < 64; o <<= 1) {
            int t = __shfl_up(x, o);
            if (lane >= o) x += t;
        }
        int slot = base + excl32[lr] + (x - (s0 + s1));

        const int col0 = lane * 128;
        uint64_t m = v.x;
        while (m) {
            int b = __ffsll((unsigned long long)m) - 1;
            m &= m - 1;
            if (slot < MAX_E) { out[slot] = row; out[MAX_E + slot] = col0 + b; }
            slot++;
        }
        m = v.y;
        while (m) {
            int b = __ffsll((unsigned long long)m) - 1;
            m &= m - 1;
            if (slot < MAX_E) { out[slot] = row; out[MAX_E + slot] = col0 + 64 + b; }
            slot++;
        }
    }
}

extern "C" void kernel_launch(void* const* d_in, const int* in_sizes, int n_in,
                              void* d_out, int out_size, void* d_ws, size_t ws_size,
                              hipStream_t stream) {
    const float* posf = (const float*)d_in[0];
    int* out = (int*)d_out;
    char* ws = (char*)d_ws;
    int*      counts = (int*)ws;                        // 32KB @ 0
    unsigned* gcount = (unsigned*)(ws + (64 << 10));    // 729 uints @ 64KB (poisoned)
    unsigned* cursor = (unsigned*)(ws + (72 << 10));    // 729 uints @ 72KB (poisoned)
    int*      cbase  = (int*)(ws + (80 << 10));         // 730 ints @ 80KB
    int*      colidx = (int*)(ws + (128 << 10));        // 8192 ints = 32KB @ 128KB
    float4*   colpts = (float4*)(ws + (192 << 10));     // 8192 float4 = 128KB @ 192KB
    uint64_t* masks  = (uint64_t*)(ws + (1 << 20));     // 8MB @ 1MB

    count_kernel<<<N / 256, 256, 0, stream>>>(posf, gcount);
    scatter_kernel<<<N / 256, 256, 0, stream>>>(posf, gcount, cursor, cbase,
                                                colpts, colidx);
    mask_kernel<<<N / M_WAVES, 256, 0, stream>>>(posf, cbase, colpts, colidx,
                                                 masks, counts, out);
    emit_kernel<<<E_BLOCKS, 256, 0, stream>>>(masks, counts, out);
}

// Round 5
// 81.010 us; speedup vs baseline: 1.0740x; 1.0135x over previous
//
#include <hip/hip_runtime.h>
#include <stdint.h>

#define N 8192
#define MAX_E (64 * N)          // 524288
#define NCHUNK (N / 64)         // 128 mask chunks per row
#define NCOL1 9                 // 9x9x9 grid, width 50/9 = 5.556 > 5 + eps
#define NCELLS (NCOL1 * NCOL1 * NCOL1)   // 729 cells
#define SCALE (9.0f / 50.0f)
#define POISON 0xAAAAAAAAu      // harness poisons d_ws to 0xAA before EVERY launch
#define M_WAVES 4               // rows per mask block (1 row per wave)
#define E_BLOCKS 256            // emit blocks (32 rows each)
#define E_ROWS 32

// Exact replication of numpy f32: sum(pos*pos, -1) = ((x*x)+(y*y))+(z*z),
// each product rounded (no fma).
__device__ __forceinline__ float sq_exact(float x, float y, float z) {
    return __fadd_rn(__fadd_rn(__fmul_rn(x, x), __fmul_rn(y, y)), __fmul_rn(z, z));
}

// d2 = RN(sqsum - RN(2*dot)); 2*dot is exact so fma(-2,dot,sqsum) is bit-identical.
// dist<5 <=> d2 < 0x1.8ffffep+4f (largest f32 below 25 has correctly-rounded sqrt
// equal to exactly 5.0, so that value must be excluded).
// |computed d2 - true d^2| <= ~7e-3, so pairs whose cells differ by >=2 in ANY
// coordinate have computed d2 > 30.8 >> threshold -> provably non-edges; the
// 3x3x3 neighbor-cell filter is bit-exact.
__device__ __forceinline__ bool edge_pred(float xi, float yi, float zi, float sqi,
                                          const float4& pj) {
    float dot = __fmaf_rn(zi, pj.z, __fmaf_rn(yi, pj.y, __fmul_rn(xi, pj.x)));
    float d2  = __fmaf_rn(-2.0f, dot, __fadd_rn(sqi, pj.w));
    return d2 < 0x1.8ffffep+4f;
}

__device__ __forceinline__ int cell_of(float v) {
    int c = (int)(__fmul_rn(v, SCALE));
    return c > 8 ? 8 : c;       // v=49.99999 -> product can round to 9.0
}

__device__ __forceinline__ int cell3_of(float x, float y, float z) {
    return (cell_of(x) * NCOL1 + cell_of(y)) * NCOL1 + cell_of(z);
}

// Pass A: count points per 3D cell. 32 parallel blocks, 8192 global atomics
// over 729 counters (~11 deep). Counts ride on the 0xAA poison base
// (documented harness contract); consumers subtract POISON.
// R2/R4 lesson: binning must stay WIDE, and launch-count is NOT the sink.
__global__ __launch_bounds__(256) void count_kernel(const float* __restrict__ posf,
                                                    unsigned* __restrict__ gcount) {
    const int i = blockIdx.x * 256 + threadIdx.x;   // grid = 32 blocks
    float x = posf[3 * i], y = posf[3 * i + 1], z = posf[3 * i + 2];
    atomicAdd(&gcount[cell3_of(x, y, z)], 1u);
}

// Pass B (fused scan+scatter): each of the 32 blocks redundantly loads the 729
// final counts (3KB, L2-hot) and exclusive-scans them -- shfl wave-scan + one
// barrier (was 16 barrier rounds). Block 0 publishes cbase[730] for mask.
// Slot assignment: cbase[cell] + (atomicAdd(cursor[cell]) - POISON); cursor is
// a second poisoned region, so no init pass and no cross-block ordering.
// Compaction => z-cells contiguous, all 8192 slots exactly written.
__global__ __launch_bounds__(256) void scatter_kernel(const float* __restrict__ posf,
                                                      const unsigned* __restrict__ gcount,
                                                      unsigned* __restrict__ cursor,
                                                      int* __restrict__ cbase_g,
                                                      float4* __restrict__ colpts,
                                                      int* __restrict__ colidx) {
    __shared__ int cb[NCELLS];
    __shared__ int wtot[4];
    const int tid  = threadIdx.x;
    const int wave = tid >> 6;
    const int lane = tid & 63;
    const int i0 = tid * 3;
    const int c0 = (i0 + 0 < NCELLS) ? (int)(gcount[i0 + 0] - POISON) : 0;
    const int c1 = (i0 + 1 < NCELLS) ? (int)(gcount[i0 + 1] - POISON) : 0;
    const int c2 = (i0 + 2 < NCELLS) ? (int)(gcount[i0 + 2] - POISON) : 0;
    const int s = c0 + c1 + c2;

    // inclusive shfl-scan of thread sums within each wave
    int x = s;
#pragma unroll
    for (int o = 1; o < 64; o <<= 1) {
        int t = __shfl_up(x, o);
        if (lane >= o) x += t;
    }
    if (lane == 63) wtot[wave] = x;
    __syncthreads();
    int woff = 0;
#pragma unroll
    for (int w = 0; w < 3; w++) woff += (wave > w) ? wtot[w] : 0;
    int run = woff + x - s;                         // exclusive prefix over threads

    if (i0 + 0 < NCELLS) { cb[i0 + 0] = run; run += c0; }
    if (i0 + 1 < NCELLS) { cb[i0 + 1] = run; run += c1; }
    if (i0 + 2 < NCELLS) { cb[i0 + 2] = run; run += c2; }
    if (blockIdx.x == 0) {
        int r2 = woff + x - s;
        if (i0 + 0 < NCELLS) { cbase_g[i0 + 0] = r2; r2 += c0; }
        if (i0 + 1 < NCELLS) { cbase_g[i0 + 1] = r2; r2 += c1; }
        if (i0 + 2 < NCELLS) { cbase_g[i0 + 2] = r2; r2 += c2; }
        if (tid == 0)
            cbase_g[NCELLS] = wtot[0] + wtot[1] + wtot[2] + wtot[3];  // = N = 8192
    }
    __syncthreads();

    const int i = blockIdx.x * 256 + tid;
    float px = posf[3 * i], py = posf[3 * i + 1], pz = posf[3 * i + 2];
    const int cell = cell3_of(px, py, pz);
    const int slot = cb[cell] + (int)(atomicAdd(&cursor[cell], 1u) - POISON);
    colpts[slot] = make_float4(px, py, pz, sq_exact(px, py, pz));
    colidx[slot] = i;
}

// Pass 1: one wave per row. NEW (R5): the 9 neighbor ranges are fused into ONE
// compact candidate index space via an in-register prefix over segment lengths;
// each lane resolves its segment with an 8-step predicated select (all
// compile-time-constant array indices -> registers, no scratch). Lane
// utilization ~53% -> ~100%; dependent gather batches/row ~12 -> ~5, and mask
// is batch-latency-bound (R0->R1 calibration: ~1us/batch).
// Also blanket-fills out[] with -1 (one int2/thread) so emit needs no tail fill.
// NO fences (R8 lesson); inter-kernel visibility guaranteed by stream order.
__global__ __launch_bounds__(256) void mask_kernel(const float* __restrict__ posf,
                                                   const int* __restrict__ cbase,
                                                   const float4* __restrict__ colpts,
                                                   const int* __restrict__ colidx,
                                                   uint64_t* __restrict__ masks,
                                                   int* __restrict__ counts,
                                                   int* __restrict__ out) {
    __shared__ uint32_t lmask[M_WAVES][256];   // 1KB bitmap per row
    const int tid  = threadIdx.x;
    const int wave = tid >> 6;
    const int lane = tid & 63;
    const int row  = blockIdx.x * M_WAVES + wave;

    // -1 prefill of the whole output (2*MAX_E ints == 2048*256 int2 exactly);
    // emit later overwrites [0, E) with edges.
    int2 neg; neg.x = -1; neg.y = -1;
    ((int2*)out)[blockIdx.x * 256 + tid] = neg;

#pragma unroll
    for (int k = lane; k < 256; k += 64) lmask[wave][k] = 0;

    const float xi = posf[3 * row], yi = posf[3 * row + 1], zi = posf[3 * row + 2];
    const float sqi = sq_exact(xi, yi, zi);
    const int cx = cell_of(xi), cy = cell_of(yi), cz = cell_of(zi);
    const int zlo = (cz > 0) ? cz - 1 : 0;
    const int zhi = (cz < 8) ? cz + 1 : 8;
    __syncthreads();

    // Segment descriptors + in-register exclusive prefix (wave-uniform).
    int starts[9], prefix[9];
    int total = 0;
#pragma unroll
    for (int q = 0; q < 9; q++) {
        const int nx = cx + q / 3 - 1;
        const int ny = cy + q % 3 - 1;
        const bool v = ((unsigned)nx <= 8u) & ((unsigned)ny <= 8u);
        const int col = v ? nx * NCOL1 + ny : 0;
        const int s0 = cbase[col * NCOL1 + zlo];
        const int e0 = cbase[col * NCOL1 + zhi + 1];
        const int len = v ? (e0 - s0) : 0;
        starts[q] = s0;
        prefix[q] = total;
        total += len;
    }

    // One fused loop over the compact candidate space: ~total/64 batches,
    // full lane occupancy. Segment select keeps scalars (no dynamic indexing).
    for (int k = lane; k < total; k += 64) {
        int sbase = starts[0];
        int soff  = 0;
#pragma unroll
        for (int t = 1; t < 9; t++) {
            const bool sel = (k >= prefix[t]);
            sbase = sel ? starts[t] : sbase;
            soff  = sel ? prefix[t] : soff;
        }
        const int a = sbase + (k - soff);
        float4 pj = colpts[a];
        int j = colidx[a];
        if (j != row && edge_pred(xi, yi, zi, sqi, pj))
            atomicOr(&lmask[wave][j >> 5], 1u << (j & 31));
    }
    __syncthreads();

    // readback: lane l holds words 4l..4l+3 = chunks 2l, 2l+1
    uint4 u = ((const uint4*)lmask[wave])[lane];
    uint64_t k0 = (uint64_t)u.x | ((uint64_t)u.y << 32);
    uint64_t k1 = (uint64_t)u.z | ((uint64_t)u.w << 32);
    ulonglong2 v; v.x = k0; v.y = k1;
    ((ulonglong2*)(masks + (size_t)row * NCHUNK))[lane] = v;
    int t = __popcll(k0) + __popcll(k1);
#pragma unroll
    for (int o = 32; o > 0; o >>= 1) t += __shfl_down(t, o);
    if (lane == 0) counts[row] = t;
}

// Pass 2: masks -> ordered edge list. 256 blocks x 32 rows. Each block
// redundantly recomputes the row-offset scan from counts (32KB, L2-hot) --
// now via shfl wave-scans (2 barriers, was 16+ rounds). No tail fill.
__global__ __launch_bounds__(256) void emit_kernel(const uint64_t* __restrict__ masks,
                                                   const int* __restrict__ counts,
                                                   int* __restrict__ out) {
    const int tid  = threadIdx.x;
    const int wave = tid >> 6;
    const int lane = tid & 63;
    const int row0 = blockIdx.x * E_ROWS;

    __shared__ int incl[256];
    __shared__ int wtot[4];
    __shared__ int excl32[32];

    // thread t sums rows [t*32, t*32+32)
    const int4* c4 = (const int4*)counts;
    int s = 0;
#pragma unroll
    for (int k = 0; k < 8; k++) {
        int4 v = c4[tid * 8 + k];
        s += v.x + v.y + v.z + v.w;
    }
    // inclusive shfl-scan within wave
    int x = s;
#pragma unroll
    for (int o = 1; o < 64; o <<= 1) {
        int t = __shfl_up(x, o);
        if (lane >= o) x += t;
    }
    if (lane == 63) wtot[wave] = x;

    // wave 0, lanes 0..31: exclusive scan of this block's 32 row counts
    if (tid < 32) {
        int c = counts[row0 + tid];
        int y = c;
#pragma unroll
        for (int o = 1; o < 32; o <<= 1) {
            int t = __shfl_up(y, o, 32);
            if (tid >= o) y += t;
        }
        excl32[tid] = y - c;
    }
    __syncthreads();
    int woff = 0;
#pragma unroll
    for (int w = 0; w < 3; w++) woff += (wave > w) ? wtot[w] : 0;
    incl[tid] = woff + x;
    __syncthreads();
    const int base = (blockIdx.x > 0) ? incl[blockIdx.x - 1] : 0;

#pragma unroll
    for (int r = 0; r < 8; r++) {
        const int lr  = wave * 8 + r;          // 0..31
        const int row = row0 + lr;
        ulonglong2 v = ((const ulonglong2*)(masks + (size_t)row * NCHUNK))[lane];
        int s0 = __popcll(v.x), s1 = __popcll(v.y);
        int xs = s0 + s1;
#pragma unroll
        for (int o = 1; o < 64; o <<= 1) {
            int t = __shfl_up(xs, o);
            if (lane >= o) xs += t;
        }
        int slot = base + excl32[lr] + (xs - (s0 + s1));

        const int col0 = lane * 128;
        uint64_t m = v.x;
        while (m) {
            int b = __ffsll((unsigned long long)m) - 1;
            m &= m - 1;
            if (slot < MAX_E) { out[slot] = row; out[MAX_E + slot] = col0 + b; }
            slot++;
        }
        m = v.y;
        while (m) {
            int b = __ffsll((unsigned long long)m) - 1;
            m &= m - 1;
            if (slot < MAX_E) { out[slot] = row; out[MAX_E + slot] = col0 + 64 + b; }
            slot++;
        }
    }
}

extern "C" void kernel_launch(void* const* d_in, const int* in_sizes, int n_in,
                              void* d_out, int out_size, void* d_ws, size_t ws_size,
                              hipStream_t stream) {
    const float* posf = (const float*)d_in[0];
    int* out = (int*)d_out;
    char* ws = (char*)d_ws;
    int*      counts = (int*)ws;                        // 32KB @ 0
    unsigned* gcount = (unsigned*)(ws + (64 << 10));    // 729 uints @ 64KB (poisoned)
    unsigned* cursor = (unsigned*)(ws + (72 << 10));    // 729 uints @ 72KB (poisoned)
    int*      cbase  = (int*)(ws + (80 << 10));         // 730 ints @ 80KB
    int*      colidx = (int*)(ws + (128 << 10));        // 8192 ints = 32KB @ 128KB
    float4*   colpts = (float4*)(ws + (192 << 10));     // 8192 float4 = 128KB @ 192KB
    uint64_t* masks  = (uint64_t*)(ws + (1 << 20));     // 8MB @ 1MB

    count_kernel<<<N / 256, 256, 0, stream>>>(posf, gcount);
    scatter_kernel<<<N / 256, 256, 0, stream>>>(posf, gcount, cursor, cbase,
                                                colpts, colidx);
    mask_kernel<<<N / M_WAVES, 256, 0, stream>>>(posf, cbase, colpts, colidx,
                                                 masks, counts, out);
    emit_kernel<<<E_BLOCKS, 256, 0, stream>>>(masks, counts, out);
}

// Round 7
// 79.026 us; speedup vs baseline: 1.1010x; 1.0251x over previous
//
#include <hip/hip_runtime.h>
#include <stdint.h>

#define N 8192
#define MAX_E (64 * N)          // 524288
#define NCHUNK (N / 64)         // 128 mask chunks per row
#define NCOL1 9                 // 9x9x9 grid, width 50/9 = 5.556 > 5 + eps
#define NCELLS (NCOL1 * NCOL1 * NCOL1)   // 729 cells
#define CAP 40                  // cell capacity: lambda=11.2, P(any cell>40)~1e-12
#define SCALE (9.0f / 50.0f)
#define POISON 0xAAAAAAAAu      // harness poisons d_ws to 0xAA before EVERY launch
#define M_WAVES 4               // rows per mask block (1 row per wave)
#define E_BLOCKS 256            // emit blocks (32 rows each)
#define E_ROWS 32

// Exact replication of numpy f32: sum(pos*pos, -1) = ((x*x)+(y*y))+(z*z),
// each product rounded (no fma).
__device__ __forceinline__ float sq_exact(float x, float y, float z) {
    return __fadd_rn(__fadd_rn(__fmul_rn(x, x), __fmul_rn(y, y)), __fmul_rn(z, z));
}

// d2 = RN(sqsum - RN(2*dot)); 2*dot is exact so fma(-2,dot,sqsum) is bit-identical.
// dist<5 <=> d2 < 0x1.8ffffep+4f (largest f32 below 25 has correctly-rounded sqrt
// equal to exactly 5.0, so that value must be excluded).
// |computed d2 - true d^2| <= ~7e-3, so pairs whose cells differ by >=2 in ANY
// coordinate have computed d2 > 30.8 >> threshold -> provably non-edges; the
// 3x3x3 neighbor-cell filter is bit-exact.
__device__ __forceinline__ bool edge_pred(float xi, float yi, float zi, float sqi,
                                          const float4& pj) {
    float dot = __fmaf_rn(zi, pj.z, __fmaf_rn(yi, pj.y, __fmul_rn(xi, pj.x)));
    float d2  = __fmaf_rn(-2.0f, dot, __fadd_rn(sqi, pj.w));
    return d2 < 0x1.8ffffep+4f;
}

__device__ __forceinline__ int cell_of(float v) {
    int c = (int)(__fmul_rn(v, SCALE));
    return c > 8 ? 8 : c;       // v=49.99999 -> product can round to 9.0
}

__device__ __forceinline__ int cell3_of(float x, float y, float z) {
    return (cell_of(x) * NCOL1 + cell_of(y)) * NCOL1 + cell_of(z);
}

// Single-pass binning (R0 pattern, now 3D cells): 32 wide blocks, slot from
// atomicAdd on the 0xAA-poisoned counter (documented harness contract).
// No count pass, no scan, no compaction: cell c owns slots [c*CAP, c*CAP+cnt).
// The z-window of a column spans ADJACENT cells, so mask addresses it with a
// 2-compare select. R2/R4/R6 lessons: stay wide, no coop, fewer dep hops.
__global__ __launch_bounds__(256) void bin_kernel(const float* __restrict__ posf,
                                                  unsigned* __restrict__ gcount,
                                                  float4* __restrict__ colpts,
                                                  int* __restrict__ colidx) {
    const int i = blockIdx.x * 256 + threadIdx.x;   // grid = 32 blocks
    float x = posf[3 * i], y = posf[3 * i + 1], z = posf[3 * i + 2];
    const int cell = cell3_of(x, y, z);
    unsigned p = atomicAdd(&gcount[cell], 1u) - POISON;
    if (p < CAP) {
        colpts[cell * CAP + p] = make_float4(x, y, z, sq_exact(x, y, z));
        colidx[cell * CAP + p] = i;
    }
}

// Pass 1: one wave per row. Per neighbor column (<=9, wave-uniform), fuse the
// 2-3 z-window cells into one candidate space with a branchless 2-compare
// select (cells adjacent in the CAP layout). ~306 avg candidates/row.
// Barrier-free: lmask[wave] is wave-private; wave_barrier() only pins compiler
// ordering (zero cost). Also blanket-fills out[] with -1 (one int2/thread,
// hidden under gather latency) so emit needs no tail fill.
// NO fences (R8 lesson); inter-kernel visibility guaranteed by stream order.
__global__ __launch_bounds__(256) void mask_kernel(const float* __restrict__ posf,
                                                   const unsigned* __restrict__ gcount,
                                                   const float4* __restrict__ colpts,
                                                   const int* __restrict__ colidx,
                                                   uint64_t* __restrict__ masks,
                                                   int* __restrict__ counts,
                                                   int* __restrict__ out) {
    __shared__ uint32_t lmask[M_WAVES][256];   // 1KB bitmap per wave/row
    const int tid  = threadIdx.x;
    const int wave = tid >> 6;
    const int lane = tid & 63;
    const int row  = blockIdx.x * M_WAVES + wave;

    // -1 prefill of the whole output (2*MAX_E ints == 2048*256 int2 exactly);
    // emit later overwrites [0, E) with edges.
    int2 neg; neg.x = -1; neg.y = -1;
    ((int2*)out)[blockIdx.x * 256 + tid] = neg;

#pragma unroll
    for (int k = lane; k < 256; k += 64) lmask[wave][k] = 0;
    __builtin_amdgcn_wave_barrier();           // ordering only; no exec cost

    const float xi = posf[3 * row], yi = posf[3 * row + 1], zi = posf[3 * row + 2];
    const float sqi = sq_exact(xi, yi, zi);
    const int cx = cell_of(xi), cy = cell_of(yi), cz = cell_of(zi);
    const int zlo = (cz > 0) ? cz - 1 : 0;
    const int zhi = (cz < 8) ? cz + 1 : 8;     // window is always 2-3 cells

    for (int dx = -1; dx <= 1; dx++) {
        const int nx = cx + dx;
        if ((unsigned)nx > 8u) continue;       // wave-uniform branch
        for (int dy = -1; dy <= 1; dy++) {
            const int ny = cy + dy;
            if ((unsigned)ny > 8u) continue;
            const int c0 = (nx * NCOL1 + ny) * NCOL1 + zlo;
            int l0 = (int)(gcount[c0] - POISON);     l0 = l0 > CAP ? CAP : l0;
            int l1 = (int)(gcount[c0 + 1] - POISON); l1 = l1 > CAP ? CAP : l1;
            int l2 = 0;
            if (zhi - zlo == 2) {
                l2 = (int)(gcount[c0 + 2] - POISON); l2 = l2 > CAP ? CAP : l2;
            }
            const int t01 = l0 + l1;
            const int tot = t01 + l2;
            for (int k = lane; k < tot; k += 64) {
                // branchless 3-segment select over adjacent cells
                const int cellk = c0 + (k >= l0) + (k >= t01);
                const int off = k - ((k >= l0) ? l0 : 0) - ((k >= t01) ? l1 : 0);
                const int a = cellk * CAP + off;
                float4 pj = colpts[a];
                int j = colidx[a];
                if (j != row && edge_pred(xi, yi, zi, sqi, pj))
                    atomicOr(&lmask[wave][j >> 5], 1u << (j & 31));
            }
        }
    }
    __builtin_amdgcn_wave_barrier();           // ordering only; no exec cost

    // readback: lane l holds words 4l..4l+3 = bit-chunks [128l, 128l+128)
    uint4 u = ((const uint4*)lmask[wave])[lane];
    uint64_t k0 = (uint64_t)u.x | ((uint64_t)u.y << 32);
    uint64_t k1 = (uint64_t)u.z | ((uint64_t)u.w << 32);
    ulonglong2 v; v.x = k0; v.y = k1;
    ((ulonglong2*)(masks + (size_t)row * NCHUNK))[lane] = v;
    int t = __popcll(k0) + __popcll(k1);
#pragma unroll
    for (int o = 32; o > 0; o >>= 1) t += __shfl_down(t, o);
    if (lane == 0) counts[row] = t;
}

// Pass 2: masks -> ordered edge list. 256 blocks x 32 rows. Each block
// redundantly recomputes the row-offset scan from counts (32KB, L2-hot) via
// shfl wave-scans (2 barriers). No tail fill (done in mask).
__global__ __launch_bounds__(256) void emit_kernel(const uint64_t* __restrict__ masks,
                                                   const int* __restrict__ counts,
                                                   int* __restrict__ out) {
    const int tid  = threadIdx.x;
    const int wave = tid >> 6;
    const int lane = tid & 63;
    const int row0 = blockIdx.x * E_ROWS;

    __shared__ int incl[256];
    __shared__ int wtot[4];
    __shared__ int excl32[32];

    // thread t sums rows [t*32, t*32+32)
    const int4* c4 = (const int4*)counts;
    int s = 0;
#pragma unroll
    for (int k = 0; k < 8; k++) {
        int4 v = c4[tid * 8 + k];
        s += v.x + v.y + v.z + v.w;
    }
    // inclusive shfl-scan within wave
    int x = s;
#pragma unroll
    for (int o = 1; o < 64; o <<= 1) {
        int t = __shfl_up(x, o);
        if (lane >= o) x += t;
    }
    if (lane == 63) wtot[wave] = x;

    // wave 0, lanes 0..31: exclusive scan of this block's 32 row counts
    if (tid < 32) {
        int c = counts[row0 + tid];
        int y = c;
#pragma unroll
        for (int o = 1; o < 32; o <<= 1) {
            int t = __shfl_up(y, o, 32);
            if (tid >= o) y += t;
        }
        excl32[tid] = y - c;
    }
    __syncthreads();
    int woff = 0;
#pragma unroll
    for (int w = 0; w < 3; w++) woff += (wave > w) ? wtot[w] : 0;
    incl[tid] = woff + x;
    __syncthreads();
    const int base = (blockIdx.x > 0) ? incl[blockIdx.x - 1] : 0;

#pragma unroll
    for (int r = 0; r < 8; r++) {
        const int lr  = wave * 8 + r;          // 0..31
        const int row = row0 + lr;
        ulonglong2 v = ((const ulonglong2*)(masks + (size_t)row * NCHUNK))[lane];
        int s0 = __popcll(v.x), s1 = __popcll(v.y);
        int xs = s0 + s1;
#pragma unroll
        for (int o = 1; o < 64; o <<= 1) {
            int t = __shfl_up(xs, o);
            if (lane >= o) xs += t;
        }
        int slot = base + excl32[lr] + (xs - (s0 + s1));

        const int col0 = lane * 128;
        uint64_t m = v.x;
        while (m) {
            int b = __ffsll((unsigned long long)m) - 1;
            m &= m - 1;
            if (slot < MAX_E) { out[slot] = row; out[MAX_E + slot] = col0 + b; }
            slot++;
        }
        m = v.y;
        while (m) {
            int b = __ffsll((unsigned long long)m) - 1;
            m &= m - 1;
            if (slot < MAX_E) { out[slot] = row; out[MAX_E + slot] = col0 + 64 + b; }
            slot++;
        }
    }
}

extern "C" void kernel_launch(void* const* d_in, const int* in_sizes, int n_in,
                              void* d_out, int out_size, void* d_ws, size_t ws_size,
                              hipStream_t stream) {
    const float* posf = (const float*)d_in[0];
    int* out = (int*)d_out;
    char* ws = (char*)d_ws;
    int*      counts = (int*)ws;                        // 32KB @ 0
    unsigned* gcount = (unsigned*)(ws + (64 << 10));    // 729 uints @ 64KB (poisoned)
    int*      colidx = (int*)(ws + (128 << 10));        // 729*40 ints = 114KB @ 128KB
    float4*   colpts = (float4*)(ws + (256 << 10));     // 729*40 float4 = 456KB @ 256KB
    uint64_t* masks  = (uint64_t*)(ws + (1 << 20));     // 8MB @ 1MB

    bin_kernel<<<N / 256, 256, 0, stream>>>(posf, gcount, colpts, colidx);
    mask_kernel<<<N / M_WAVES, 256, 0, stream>>>(posf, gcount, colpts, colidx,
                                                 masks, counts, out);
    emit_kernel<<<E_BLOCKS, 256, 0, stream>>>(masks, counts, out);
}

// Round 8
// 74.724 us; speedup vs baseline: 1.1644x; 1.0576x over previous
//
#include <hip/hip_runtime.h>
#include <stdint.h>

#define N 8192
#define MAX_E (64 * N)          // 524288
#define NCOL1 9                 // 9x9x9 grid, width 50/9 = 5.556 > 5 + eps
#define NCELLS (NCOL1 * NCOL1 * NCOL1)   // 729 cells
#define CAP 40                  // cell capacity: lambda=11.2, P(any cell>40)~1e-12
#define RCAP 128                // per-row neighbor-list capacity (lambda~34, P>128 ~ 0)
#define SCALE (9.0f / 50.0f)
#define POISON 0xAAAAAAAAu      // harness poisons d_ws to 0xAA before EVERY launch
#define M_WAVES 4               // rows per mask block (1 row per wave)
#define E_BLOCKS 256            // emit blocks (32 rows each)
#define E_ROWS 32

// Exact replication of numpy f32: sum(pos*pos, -1) = ((x*x)+(y*y))+(z*z),
// each product rounded (no fma).
__device__ __forceinline__ float sq_exact(float x, float y, float z) {
    return __fadd_rn(__fadd_rn(__fmul_rn(x, x), __fmul_rn(y, y)), __fmul_rn(z, z));
}

// d2 = RN(sqsum - RN(2*dot)); 2*dot is exact so fma(-2,dot,sqsum) is bit-identical.
// dist<5 <=> d2 < 0x1.8ffffep+4f (largest f32 below 25 has correctly-rounded sqrt
// equal to exactly 5.0, so that value must be excluded).
// |computed d2 - true d^2| <= ~7e-3, so pairs whose cells differ by >=2 in ANY
// coordinate have computed d2 > 30.8 >> threshold -> provably non-edges; the
// 3x3x3 neighbor-cell filter is bit-exact.
// sq_j is recomputed here from (x,y,z) -- bit-identical to the bin-side value
// (same deterministic op sequence), freeing pj.w to carry the point index.
__device__ __forceinline__ bool edge_pred(float xi, float yi, float zi, float sqi,
                                          float px, float py, float pz) {
    float sqj = sq_exact(px, py, pz);
    float dot = __fmaf_rn(zi, pz, __fmaf_rn(yi, py, __fmul_rn(xi, px)));
    float d2  = __fmaf_rn(-2.0f, dot, __fadd_rn(sqi, sqj));
    return d2 < 0x1.8ffffep+4f;
}

__device__ __forceinline__ int cell_of(float v) {
    int c = (int)(__fmul_rn(v, SCALE));
    return c > 8 ? 8 : c;       // v=49.99999 -> product can round to 9.0
}

__device__ __forceinline__ int cell3_of(float x, float y, float z) {
    return (cell_of(x) * NCOL1 + cell_of(y)) * NCOL1 + cell_of(z);
}

// Single-pass 3D binning (R7 structure): 32 wide blocks, slot from atomicAdd
// on the 0xAA-poisoned counter (documented harness contract). Cell c owns
// slots [c*CAP, c*CAP+cnt). NEW: the point index rides in colpts.w as int
// bits -> mask does ONE float4 load per candidate (no colidx buffer at all).
__global__ __launch_bounds__(256) void bin_kernel(const float* __restrict__ posf,
                                                  unsigned* __restrict__ gcount,
                                                  float4* __restrict__ colpts) {
    const int i = blockIdx.x * 256 + threadIdx.x;   // grid = 32 blocks
    float x = posf[3 * i], y = posf[3 * i + 1], z = posf[3 * i + 2];
    const int cell = cell3_of(x, y, z);
    unsigned p = atomicAdd(&gcount[cell], 1u) - POISON;
    if (p < CAP) {
        colpts[cell * CAP + p] = make_float4(x, y, z, __int_as_float(i));
    }
}

// Pass 1: one wave per row. Gathers ~306 candidates from the 9 neighbor
// columns (z-window cells adjacent in the CAP layout; branchless 2-compare
// select), builds the row bitmap in wave-private LDS, then COMPACTS it
// in-kernel: wave-scan of per-lane popcounts -> sorted u16 col list written
// to stage[row*RCAP] (bit position = col, so the list is sorted for free).
// This kills the 8MB masks round-trip (now ~2MB u16). counts[row] = degree.
// Also blanket-fills out[] with -1 (one int2/thread, hidden under gathers).
// NO fences (R8 lesson); inter-kernel visibility guaranteed by stream order.
__global__ __launch_bounds__(256) void mask_kernel(const float* __restrict__ posf,
                                                   const unsigned* __restrict__ gcount,
                                                   const float4* __restrict__ colpts,
                                                   uint16_t* __restrict__ stage,
                                                   int* __restrict__ counts,
                                                   int* __restrict__ out) {
    __shared__ uint32_t lmask[M_WAVES][256];   // 1KB bitmap per wave/row
    const int tid  = threadIdx.x;
    const int wave = tid >> 6;
    const int lane = tid & 63;
    const int row  = blockIdx.x * M_WAVES + wave;

    // -1 prefill of the whole output (2*MAX_E ints == 2048*256 int2 exactly);
    // emit later overwrites [0, E) with edges.
    int2 neg; neg.x = -1; neg.y = -1;
    ((int2*)out)[blockIdx.x * 256 + tid] = neg;

#pragma unroll
    for (int k = lane; k < 256; k += 64) lmask[wave][k] = 0;
    __builtin_amdgcn_wave_barrier();           // ordering only; no exec cost

    const float xi = posf[3 * row], yi = posf[3 * row + 1], zi = posf[3 * row + 2];
    const float sqi = sq_exact(xi, yi, zi);
    const int cx = cell_of(xi), cy = cell_of(yi), cz = cell_of(zi);
    const int zlo = (cz > 0) ? cz - 1 : 0;
    const int zhi = (cz < 8) ? cz + 1 : 8;     // window is always 2-3 cells

    for (int dx = -1; dx <= 1; dx++) {
        const int nx = cx + dx;
        if ((unsigned)nx > 8u) continue;       // wave-uniform branch
        for (int dy = -1; dy <= 1; dy++) {
            const int ny = cy + dy;
            if ((unsigned)ny > 8u) continue;
            const int c0 = (nx * NCOL1 + ny) * NCOL1 + zlo;
            int l0 = (int)(gcount[c0] - POISON);     l0 = l0 > CAP ? CAP : l0;
            int l1 = (int)(gcount[c0 + 1] - POISON); l1 = l1 > CAP ? CAP : l1;
            int l2 = 0;
            if (zhi - zlo == 2) {
                l2 = (int)(gcount[c0 + 2] - POISON); l2 = l2 > CAP ? CAP : l2;
            }
            const int t01 = l0 + l1;
            const int tot = t01 + l2;
            for (int k = lane; k < tot; k += 64) {
                // branchless 3-segment select over adjacent cells
                const int cellk = c0 + (k >= l0) + (k >= t01);
                const int off = k - ((k >= l0) ? l0 : 0) - ((k >= t01) ? l1 : 0);
                float4 pj = colpts[cellk * CAP + off];
                const int j = __float_as_int(pj.w);
                if (j != row && edge_pred(xi, yi, zi, sqi, pj.x, pj.y, pj.z))
                    atomicOr(&lmask[wave][j >> 5], 1u << (j & 31));
            }
        }
    }
    __builtin_amdgcn_wave_barrier();           // ordering only; no exec cost

    // readback: lane l holds words 4l..4l+3 = bit-chunks [128l, 128l+128)
    uint4 u = ((const uint4*)lmask[wave])[lane];
    uint64_t k0 = (uint64_t)u.x | ((uint64_t)u.y << 32);
    uint64_t k1 = (uint64_t)u.z | ((uint64_t)u.w << 32);
    const int pc = __popcll(k0) + __popcll(k1);
    int xs = pc;                               // inclusive wave scan
#pragma unroll
    for (int o = 1; o < 64; o <<= 1) {
        int t = __shfl_up(xs, o);
        if (lane >= o) xs += t;
    }
    if (lane == 63) counts[row] = xs;          // row degree
    int off = xs - pc;                         // this lane's start in the list

    // compact sorted col list (bit position = col => sorted for free)
    uint16_t* dst = stage + (size_t)row * RCAP;
    const int col0 = lane * 128;
    uint64_t m = k0;
    while (m) {
        int b = __ffsll((unsigned long long)m) - 1;
        m &= m - 1;
        if (off < RCAP) dst[off] = (uint16_t)(col0 + b);
        off++;
    }
    m = k1;
    while (m) {
        int b = __ffsll((unsigned long long)m) - 1;
        m &= m - 1;
        if (off < RCAP) dst[off] = (uint16_t)(col0 + 64 + b);
        off++;
    }
}

// Pass 2: trivial now -- block-redundant scan of counts (32KB, L2-hot, shfl
// wave-scans) for slot bases, then a coalesced copy of each row's u16 col
// list into the (row, col) output pair slots. No bitmaps, no ffs loops.
__global__ __launch_bounds__(256) void emit_kernel(const uint16_t* __restrict__ stage,
                                                   const int* __restrict__ counts,
                                                   int* __restrict__ out) {
    const int tid  = threadIdx.x;
    const int wave = tid >> 6;
    const int lane = tid & 63;
    const int row0 = blockIdx.x * E_ROWS;

    __shared__ int incl[256];
    __shared__ int wtot[4];
    __shared__ int excl32[32];

    // thread t sums rows [t*32, t*32+32)
    const int4* c4 = (const int4*)counts;
    int s = 0;
#pragma unroll
    for (int k = 0; k < 8; k++) {
        int4 v = c4[tid * 8 + k];
        s += v.x + v.y + v.z + v.w;
    }
    int x = s;                                 // inclusive shfl-scan within wave
#pragma unroll
    for (int o = 1; o < 64; o <<= 1) {
        int t = __shfl_up(x, o);
        if (lane >= o) x += t;
    }
    if (lane == 63) wtot[wave] = x;

    // wave 0, lanes 0..31: exclusive scan of this block's 32 row counts
    if (tid < 32) {
        int c = counts[row0 + tid];
        int y = c;
#pragma unroll
        for (int o = 1; o < 32; o <<= 1) {
            int t = __shfl_up(y, o, 32);
            if (tid >= o) y += t;
        }
        excl32[tid] = y - c;
    }
    __syncthreads();
    int woff = 0;
#pragma unroll
    for (int w = 0; w < 3; w++) woff += (wave > w) ? wtot[w] : 0;
    incl[tid] = woff + x;
    __syncthreads();
    const int base = (blockIdx.x > 0) ? incl[blockIdx.x - 1] : 0;

#pragma unroll
    for (int r = 0; r < 8; r++) {
        const int lr  = wave * 8 + r;          // 0..31
        const int row = row0 + lr;
        int c = counts[row];
        c = c > RCAP ? RCAP : c;
        const int slot = base + excl32[lr];
        const uint16_t* src = stage + (size_t)row * RCAP;
        for (int k = lane; k < c; k += 64) {
            const int sk = slot + k;
            if (sk < MAX_E) {
                out[sk] = row;
                out[MAX_E + sk] = (int)src[k];
            }
        }
    }
}

extern "C" void kernel_launch(void* const* d_in, const int* in_sizes, int n_in,
                              void* d_out, int out_size, void* d_ws, size_t ws_size,
                              hipStream_t stream) {
    const float* posf = (const float*)d_in[0];
    int* out = (int*)d_out;
    char* ws = (char*)d_ws;
    int*      counts = (int*)ws;                        // 32KB @ 0
    unsigned* gcount = (unsigned*)(ws + (64 << 10));    // 729 uints @ 64KB (poisoned)
    float4*   colpts = (float4*)(ws + (256 << 10));     // 729*40 float4 = 456KB @ 256KB
    uint16_t* stage  = (uint16_t*)(ws + (1 << 20));     // 8192*128 u16 = 2MB @ 1MB

    bin_kernel<<<N / 256, 256, 0, stream>>>(posf, gcount, colpts);
    mask_kernel<<<N / M_WAVES, 256, 0, stream>>>(posf, gcount, colpts,
                                                 stage, counts, out);
    emit_kernel<<<E_BLOCKS, 256, 0, stream>>>(stage, counts, out);
}